// Round 8
// baseline (326.665 us; speedup 1.0000x reference)
//
#include <hip/hip_runtime.h>
#include <math.h>

#define HN 16
#define SEQ 1024
#define DMODEL 1024
#define DH 64
#define SM1 1023   // S-1

typedef float  f32x4  __attribute__((ext_vector_type(4)));
typedef __bf16 bf16x8 __attribute__((ext_vector_type(8)));

#define ROWB 272   // LDS row stride bytes: 16 slots of 16B + 1 pad slot

// ---------------------------------------------------------------
// MFMA GEMM with bf16 hi/lo split (3 MFMAs ~ fp32 precision).
// MODE 0: head-split bf16 hi/lo planes out[bh][s(SEQ)][64]
// MODE 1: plain fp32 out[m][1024]
// MODE 2: transposed bf16 hi/lo planes out[bh][dh][1024(pad)]
// ---------------------------------------------------------------
template<int MODE>
__global__ __launch_bounds__(256)
void gemm_mfma_kernel(const float* __restrict__ X, const float* __restrict__ W,
                      const float* __restrict__ bias, float* __restrict__ out32,
                      __bf16* __restrict__ outHi, __bf16* __restrict__ outLo,
                      int M, int rows)
{
    __shared__ __align__(16) __bf16 As[4096];
    __shared__ __align__(16) __bf16 Bs[4096];

    const int t  = threadIdx.x;
    const int w  = t >> 6, l = t & 63;
    const int lr = l & 15, ls = l >> 4;
    const int m0 = blockIdx.y * 64, n0 = blockIdx.x * 64;
    const int sr  = t >> 2;
    const int skq = t & 3;

    f32x4 acc[4];
#pragma unroll
    for (int ct = 0; ct < 4; ++ct) acc[ct] = f32x4{0.f, 0.f, 0.f, 0.f};

    const int ar   = w * 16 + lr;
    const int a_hi = ar * 128 + (((2 * ls    ) ^ (ar & 7)) << 4);
    const int a_lo = ar * 128 + (((2 * ls + 1) ^ (ar & 7)) << 4);
    const int st_hi = sr * 128 + (((2 * skq    ) ^ (sr & 7)) << 4);
    const int st_lo = sr * 128 + (((2 * skq + 1) ^ (sr & 7)) << 4);

    for (int k0 = 0; k0 < DMODEL; k0 += 32) {
        __syncthreads();
        {
            float xv[8];
            if (m0 + sr < M) {
                float4 v0 = *(const float4*)&X[(size_t)(m0 + sr) * DMODEL + k0 + skq * 8];
                float4 v1 = *(const float4*)&X[(size_t)(m0 + sr) * DMODEL + k0 + skq * 8 + 4];
                xv[0] = v0.x; xv[1] = v0.y; xv[2] = v0.z; xv[3] = v0.w;
                xv[4] = v1.x; xv[5] = v1.y; xv[6] = v1.z; xv[7] = v1.w;
            } else {
#pragma unroll
                for (int e = 0; e < 8; ++e) xv[e] = 0.f;
            }
            bf16x8 h8, l8;
#pragma unroll
            for (int e = 0; e < 8; ++e) {
                __bf16 hb = (__bf16)xv[e];
                h8[e] = hb;
                l8[e] = (__bf16)(xv[e] - (float)hb);
            }
            *(bf16x8*)((char*)As + st_hi) = h8;
            *(bf16x8*)((char*)As + st_lo) = l8;
        }
        {
            float wv[8];
#pragma unroll
            for (int e = 0; e < 8; ++e)
                wv[e] = W[(size_t)(k0 + skq * 8 + e) * DMODEL + n0 + sr];
            bf16x8 h8, l8;
#pragma unroll
            for (int e = 0; e < 8; ++e) {
                __bf16 hb = (__bf16)wv[e];
                h8[e] = hb;
                l8[e] = (__bf16)(wv[e] - (float)hb);
            }
            *(bf16x8*)((char*)Bs + st_hi) = h8;
            *(bf16x8*)((char*)Bs + st_lo) = l8;
        }
        __syncthreads();

        const bf16x8 ah = *(const bf16x8*)((const char*)As + a_hi);
        const bf16x8 al = *(const bf16x8*)((const char*)As + a_lo);
#pragma unroll
        for (int ct = 0; ct < 4; ++ct) {
            const int bc   = ct * 16 + lr;
            const int b_hi = bc * 128 + (((2 * ls    ) ^ (bc & 7)) << 4);
            const int b_lo = bc * 128 + (((2 * ls + 1) ^ (bc & 7)) << 4);
            const bf16x8 bh = *(const bf16x8*)((const char*)Bs + b_hi);
            const bf16x8 bl = *(const bf16x8*)((const char*)Bs + b_lo);
            acc[ct] = __builtin_amdgcn_mfma_f32_16x16x32_bf16(ah, bh, acc[ct], 0, 0, 0);
            acc[ct] = __builtin_amdgcn_mfma_f32_16x16x32_bf16(al, bh, acc[ct], 0, 0, 0);
            acc[ct] = __builtin_amdgcn_mfma_f32_16x16x32_bf16(ah, bl, acc[ct], 0, 0, 0);
        }
    }

#pragma unroll
    for (int ct = 0; ct < 4; ++ct) {
        const int n = n0 + ct * 16 + lr;
        const float bv = bias[n];
#pragma unroll
        for (int j = 0; j < 4; ++j) {
            const int m = m0 + w * 16 + ls * 4 + j;
            if (m >= M) continue;
            const float val = acc[ct][j] + bv;
            if (MODE == 1) {
                out32[(size_t)m * DMODEL + n] = val;
            } else {
                const int bb = m / rows, s = m - bb * rows;
                const __bf16 hb = (__bf16)val;
                const __bf16 lb = (__bf16)(val - (float)hb);
                size_t idx;
                if (MODE == 0)
                    idx = (((size_t)(bb * HN + (n >> 6)) * SEQ + s) << 6) + (n & 63);
                else
                    idx = (((size_t)(bb * HN + (n >> 6)) * DH + (n & 63)) << 10) + s;
                outHi[idx] = hb; outLo[idx] = lb;
            }
        }
    }
}

// ---------------------------------------------------------------
// Pack mask [2*1023 rows][1023 cols] int32 -> bitmask [row][32 u32].
// Wave per row; 16 ballots of 64 cols.
// ---------------------------------------------------------------
__global__ __launch_bounds__(256)
void mask_pack_kernel(const int* __restrict__ mask, unsigned int* __restrict__ mb)
{
    const int row = blockIdx.x * 4 + (threadIdx.x >> 6);
    const int l   = threadIdx.x & 63;
    if (row >= 2 * SM1) return;
    const int* mrow = mask + (size_t)row * SM1;
    unsigned int* out = mb + (size_t)row * 32;
#pragma unroll
    for (int i = 0; i < 16; ++i) {
        const int c = i * 64 + l;
        const bool mv = (c < SM1) && (mrow[c] != 0);
        unsigned long long bal = __ballot(mv);
        if (l == 0) {
            out[i * 2]     = (unsigned int)bal;
            out[i * 2 + 1] = (unsigned int)(bal >> 32);
        }
    }
}

// ---------------------------------------------------------------
// QK^T -> relu/scale/mask(bits) -> exp, all LDS-fed.
// Block: 64 att-rows x 128 cols, 256 thr / 4 waves.
// ---------------------------------------------------------------
__global__ __launch_bounds__(256)
void qk_exp_kernel(const __bf16* __restrict__ qhi, const __bf16* __restrict__ qlo,
                   const __bf16* __restrict__ khi, const __bf16* __restrict__ klo,
                   const unsigned int* __restrict__ mbG, float* __restrict__ att,
                   float* __restrict__ partials)
{
    __shared__ __align__(16) char Qs[64 * ROWB];
    __shared__ __align__(16) char Ks[128 * ROWB];   // reused as exp tile [64][132] f32
    __shared__ unsigned int mbits[64][4];

    const int bh = blockIdx.z, b = bh >> 4;
    const int q0 = blockIdx.y * 64;
    const int c0 = blockIdx.x * 128;
    const int t = threadIdx.x, w = t >> 6, l = t & 63;
    const int lr = l & 15, ls = l >> 4;

    // ---- stage mask bits (1KB) ----
    {
        const int r = t >> 2, wd = t & 3;
        const int rr = q0 + r;
        unsigned int v = 0;
        if (rr < SM1) v = mbG[((size_t)b * SM1 + rr) * 32 + (c0 >> 5) + wd];
        mbits[r][wd] = v;
    }
    // ---- stage Q (64 rows x 16 chunks) ----
#pragma unroll
    for (int it = 0; it < 4; ++it) {
        const int id = t + it * 256;
        const int r = id >> 4, cw = id & 15;
        const int plane = cw >> 3, s = cw & 7;
        int qrow = q0 + r + 1; if (qrow > 1023) qrow = 1023;
        const __bf16* src = plane ? qlo : qhi;
        bf16x8 vv = *(const bf16x8*)&src[((size_t)bh * SEQ + qrow) * DH + s * 8];
        *(bf16x8*)(Qs + r * ROWB + cw * 16) = vv;
    }
    // ---- stage K (128 rows x 16 chunks) ----
#pragma unroll
    for (int it = 0; it < 8; ++it) {
        const int id = t + it * 256;
        const int r = id >> 4, cw = id & 15;
        const int plane = cw >> 3, s = cw & 7;
        int krow = c0 + r; if (krow > 1023) krow = 1023;
        const __bf16* src = plane ? klo : khi;
        bf16x8 vv = *(const bf16x8*)&src[((size_t)bh * SEQ + krow) * DH + s * 8];
        *(bf16x8*)(Ks + r * ROWB + cw * 16) = vv;
    }
    __syncthreads();

    const int ar = w * 16 + lr;
    const bf16x8 a0h = *(const bf16x8*)(Qs + ar * ROWB + ls * 16);
    const bf16x8 a1h = *(const bf16x8*)(Qs + ar * ROWB + (4 + ls) * 16);
    const bf16x8 a0l = *(const bf16x8*)(Qs + ar * ROWB + (8 + ls) * 16);
    const bf16x8 a1l = *(const bf16x8*)(Qs + ar * ROWB + (12 + ls) * 16);

    float e[8][4];
    float rsum[4] = {0.f, 0.f, 0.f, 0.f};

#pragma unroll
    for (int ct = 0; ct < 8; ++ct) {
        const int kr = ct * 16 + lr;
        const bf16x8 b0h = *(const bf16x8*)(Ks + kr * ROWB + ls * 16);
        const bf16x8 b1h = *(const bf16x8*)(Ks + kr * ROWB + (4 + ls) * 16);
        const bf16x8 b0l = *(const bf16x8*)(Ks + kr * ROWB + (8 + ls) * 16);
        const bf16x8 b1l = *(const bf16x8*)(Ks + kr * ROWB + (12 + ls) * 16);

        f32x4 acc = {0.f, 0.f, 0.f, 0.f};
        acc = __builtin_amdgcn_mfma_f32_16x16x32_bf16(a0h, b0h, acc, 0, 0, 0);
        acc = __builtin_amdgcn_mfma_f32_16x16x32_bf16(a0l, b0h, acc, 0, 0, 0);
        acc = __builtin_amdgcn_mfma_f32_16x16x32_bf16(a0h, b0l, acc, 0, 0, 0);
        acc = __builtin_amdgcn_mfma_f32_16x16x32_bf16(a1h, b1h, acc, 0, 0, 0);
        acc = __builtin_amdgcn_mfma_f32_16x16x32_bf16(a1l, b1h, acc, 0, 0, 0);
        acc = __builtin_amdgcn_mfma_f32_16x16x32_bf16(a1h, b1l, acc, 0, 0, 0);

        const int c = c0 + ct * 16 + lr;
#pragma unroll
        for (int j = 0; j < 4; ++j) {
            const int r = q0 + w * 16 + ls * 4 + j;
            float v = 0.f;
            if (r < SM1 && c < SM1) {
                float sc = fmaxf(acc[j] * 0.125f, 0.f);
                const unsigned int wmask = mbits[w * 16 + ls * 4 + j][ct >> 1];
                if ((wmask >> ((ct & 1) * 16 + lr)) & 1u) sc = -1e9f;
                v = __expf(sc);
            }
            e[ct][j] = v;
            rsum[j] += v;
        }
    }

    // partial sums over this 128-col block (reduce across lr lanes)
#pragma unroll
    for (int j = 0; j < 4; ++j) {
        rsum[j] += __shfl_xor(rsum[j], 1, 64);
        rsum[j] += __shfl_xor(rsum[j], 2, 64);
        rsum[j] += __shfl_xor(rsum[j], 4, 64);
        rsum[j] += __shfl_xor(rsum[j], 8, 64);
    }
    if (lr == 0) {
#pragma unroll
        for (int j = 0; j < 4; ++j) {
            const int r = q0 + w * 16 + ls * 4 + j;
            if (r < SM1)
                partials[(((size_t)bh << 10) + r) * 8 + blockIdx.x] = rsum[j];
        }
    }

    __syncthreads();                 // all waves done reading Ks
    float* E = (float*)Ks;           // exp tile [64][132]
#pragma unroll
    for (int ct = 0; ct < 8; ++ct)
#pragma unroll
        for (int j = 0; j < 4; ++j)
            E[(w * 16 + ls * 4 + j) * 132 + ct * 16 + lr] = e[ct][j];
    __syncthreads();

    // coalesced write of 64 rows x 128 cols
#pragma unroll
    for (int it = 0; it < 8; ++it) {
        const int id = t + it * 256;
        const int r = id >> 5, q4 = id & 31;
        const int rr = q0 + r, cc = c0 + q4 * 4;
        if (rr < SM1) {
            f32x4 vv = *(const f32x4*)&E[r * 132 + q4 * 4];
            float* dst = &att[((size_t)bh * SM1 + rr) * SM1 + cc];
            if (cc + 4 <= SM1) {
                __builtin_nontemporal_store(vv, (f32x4*)dst);
            } else {
                if (cc + 0 < SM1) dst[0] = vv.x;
                if (cc + 1 < SM1) dst[1] = vv.y;
                if (cc + 2 < SM1) dst[2] = vv.z;
            }
        }
    }
}

// ---------------------------------------------------------------
// PV + normalize. Block: 64 att-rows x 64 dh, 512 thr / 8 waves.
// ---------------------------------------------------------------
__global__ __launch_bounds__(512)
void pv_kernel(float* att, const __bf16* __restrict__ vthi,
               const __bf16* __restrict__ vtlo, const float* __restrict__ partials,
               float* __restrict__ ctx)
{
    __shared__ __align__(16) char Ps[64 * ROWB];   // reused as red buf [64][68] f32
    __shared__ __align__(16) char Vs[64 * ROWB];
    __shared__ float invs[64];

    const int bh = blockIdx.y, b = bh >> 4, h = bh & 15;
    const int q0 = blockIdx.x * 64;
    const int t = threadIdx.x, w = t >> 6, l = t & 63;
    const int lr = l & 15, ls = l >> 4;
    const int g = w & 3, p = w >> 2;

    if (t < 64) {
        const float* pp = &partials[(((size_t)bh << 10) + q0 + t) * 8];
        float s = 0.f;
#pragma unroll
        for (int i = 0; i < 8; ++i) s += pp[i];
        invs[t] = 1.0f / s;
    }

    f32x4 oacc[4];
#pragma unroll
    for (int ct = 0; ct < 4; ++ct) oacc[ct] = f32x4{0.f, 0.f, 0.f, 0.f};

    const int pr = g * 16 + lr;

    for (int kt = 0; kt < 16; ++kt) {
        const int kb0 = kt * 64;
        __syncthreads();
        // ---- stage P: 64 rows x 8 chunks of 8 floats ----
        {
            const int r = t >> 3, ch = t & 7;
            const int rr = q0 + r;
            float pf[8];
#pragma unroll
            for (int e2 = 0; e2 < 8; ++e2) pf[e2] = 0.f;
            if (rr < SM1) {
                const int cbase = kb0 + ch * 8;
                float* gp = &att[((size_t)bh * SM1 + rr) * SM1 + cbase];
                const float iv = invs[r];
                if (cbase + 8 <= SM1) {
                    f32x4 v0 = __builtin_nontemporal_load((const f32x4*)gp);
                    f32x4 v1 = __builtin_nontemporal_load((const f32x4*)(gp + 4));
                    pf[0] = v0.x * iv; pf[1] = v0.y * iv; pf[2] = v0.z * iv; pf[3] = v0.w * iv;
                    pf[4] = v1.x * iv; pf[5] = v1.y * iv; pf[6] = v1.z * iv; pf[7] = v1.w * iv;
                    f32x4 w0 = {pf[0], pf[1], pf[2], pf[3]};
                    f32x4 w1 = {pf[4], pf[5], pf[6], pf[7]};
                    __builtin_nontemporal_store(w0, (f32x4*)gp);
                    __builtin_nontemporal_store(w1, (f32x4*)(gp + 4));
                } else {
#pragma unroll
                    for (int e2 = 0; e2 < 8; ++e2) {
                        if (cbase + e2 < SM1) {
                            pf[e2] = gp[e2] * iv;
                            gp[e2] = pf[e2];
                        }
                    }
                }
            }
            bf16x8 h8, l8;
#pragma unroll
            for (int e2 = 0; e2 < 8; ++e2) {
                const __bf16 hb = (__bf16)pf[e2];
                h8[e2] = hb;
                l8[e2] = (__bf16)(pf[e2] - (float)hb);
            }
            *(bf16x8*)(Ps + r * ROWB + ch * 16) = h8;
            *(bf16x8*)(Ps + r * ROWB + (8 + ch) * 16) = l8;
        }
        // ---- stage V: 64 dh-rows x 16 chunks ----
#pragma unroll
        for (int it = 0; it < 2; ++it) {
            const int id = t + it * 512;
            const int dr = id >> 4, cw = id & 15;
            const int plane = cw >> 3, s = cw & 7;
            const __bf16* src = plane ? vtlo : vthi;
            bf16x8 vv = *(const bf16x8*)&src[(((size_t)bh * DH + dr) << 10) + kb0 + s * 8];
            *(bf16x8*)(Vs + dr * ROWB + cw * 16) = vv;
        }
        __syncthreads();

        // ---- MFMA: kstep parity p ----
        const bf16x8 ph = *(const bf16x8*)(Ps + pr * ROWB + (p * 4 + ls) * 16);
        const bf16x8 pl = *(const bf16x8*)(Ps + pr * ROWB + (8 + p * 4 + ls) * 16);
#pragma unroll
        for (int ct = 0; ct < 4; ++ct) {
            const int vr = ct * 16 + lr;
            const bf16x8 vh = *(const bf16x8*)(Vs + vr * ROWB + (p * 4 + ls) * 16);
            const bf16x8 vl = *(const bf16x8*)(Vs + vr * ROWB + (8 + p * 4 + ls) * 16);
            oacc[ct] = __builtin_amdgcn_mfma_f32_16x16x32_bf16(ph, vh, oacc[ct], 0, 0, 0);
            oacc[ct] = __builtin_amdgcn_mfma_f32_16x16x32_bf16(pl, vh, oacc[ct], 0, 0, 0);
            oacc[ct] = __builtin_amdgcn_mfma_f32_16x16x32_bf16(ph, vl, oacc[ct], 0, 0, 0);
        }
    }

    // ---- cross-parity reduce and ctx write ----
    __syncthreads();
    float* red = (float*)Ps;   // [64][68]
    if (p == 1) {
#pragma unroll
        for (int ct = 0; ct < 4; ++ct)
#pragma unroll
            for (int j = 0; j < 4; ++j)
                red[(g * 16 + ls * 4 + j) * 68 + ct * 16 + lr] = oacc[ct][j];
    }
    __syncthreads();
    if (p == 0) {
#pragma unroll
        for (int ct = 0; ct < 4; ++ct)
#pragma unroll
            for (int j = 0; j < 4; ++j) {
                const int r = q0 + g * 16 + ls * 4 + j;
                if (r < SM1)
                    ctx[((size_t)b * SM1 + r) * DMODEL + h * DH + ct * 16 + lr] =
                        oacc[ct][j] + red[(g * 16 + ls * 4 + j) * 68 + ct * 16 + lr];
            }
    }
}

// ---------------------------------------------------------------
extern "C" void kernel_launch(void* const* d_in, const int* in_sizes, int n_in,
                              void* d_out, int out_size, void* d_ws, size_t ws_size,
                              hipStream_t stream) {
    const float* q    = (const float*)d_in[0];
    const float* k    = (const float*)d_in[1];
    const float* v    = (const float*)d_in[2];
    const int*   mask = (const int*)  d_in[4];
    const float* Wq   = (const float*)d_in[5];
    const float* bq   = (const float*)d_in[6];
    const float* Wk   = (const float*)d_in[7];
    const float* bk   = (const float*)d_in[8];
    const float* Wv   = (const float*)d_in[9];
    const float* bv   = (const float*)d_in[10];
    const float* Wo   = (const float*)d_in[11];
    const float* bo   = (const float*)d_in[12];

    float* out0 = (float*)d_out;                       // [2,1023,1024]
    float* att  = out0 + (size_t)2 * SM1 * DMODEL;     // [2,16,1023,1023]

    const size_t NQ  = (size_t)2 * HN * SEQ * DH;      // 2,097,152 per plane
    const size_t NVT = (size_t)2 * HN * DH * 1024;     // 2,097,152 per plane
    __bf16* ws16 = (__bf16*)d_ws;
    __bf16* qhi  = ws16;
    __bf16* qlo  = qhi + NQ;
    __bf16* khi  = qlo + NQ;
    __bf16* klo  = khi + NQ;
    __bf16* vthi = klo + NQ;
    __bf16* vtlo = vthi + NVT;
    float*  ctx  = (float*)(vtlo + NVT);               // [2,1023,1024]
    float*  partials = ctx + (size_t)2 * SM1 * DMODEL; // [32,1024,8]
    unsigned int* mbG = (unsigned int*)(partials + (size_t)32 * 1024 * 8); // [2046][32]

    (void)hipMemsetAsync(vthi, 0, 2 * NVT * sizeof(__bf16), stream);

    mask_pack_kernel<<<dim3(512), 256, 0, stream>>>(mask, mbG);

    gemm_mfma_kernel<0><<<dim3(16, 32), 256, 0, stream>>>(q, Wq, bq, nullptr, qhi, qlo, 2 * SEQ, SEQ);
    gemm_mfma_kernel<0><<<dim3(16, 32), 256, 0, stream>>>(k, Wk, bk, nullptr, khi, klo, 2 * SEQ, SEQ);
    gemm_mfma_kernel<2><<<dim3(16, 32), 256, 0, stream>>>(v, Wv, bv, nullptr, vthi, vtlo, 2 * SM1, SM1);

    qk_exp_kernel<<<dim3(8, 16, 32), 256, 0, stream>>>(qhi, qlo, khi, klo, mbG, att, partials);
    pv_kernel<<<dim3(16, 32), 512, 0, stream>>>(att, vthi, vtlo, partials, ctx);

    gemm_mfma_kernel<1><<<dim3(16, 32), 256, 0, stream>>>(ctx, Wo, bo, out0, nullptr, nullptr, 2 * SM1, SM1);
}

// Round 9
// 265.084 us; speedup vs baseline: 1.2323x; 1.2323x over previous
//
#include <hip/hip_runtime.h>
#include <math.h>

#define HN 16
#define SEQ 1024
#define DMODEL 1024
#define DH 64
#define SM1 1023   // S-1

typedef float  f32x4  __attribute__((ext_vector_type(4)));
typedef __bf16 bf16x8 __attribute__((ext_vector_type(8)));

#define ROWB 272   // K/Q LDS row stride (16 slots of 16B + 1 pad slot)
#define VROWB 560  // V LDS row stride (32 slots of 16B + pad -> 2-way banks)

// ---------------------------------------------------------------
// MFMA GEMM with bf16 hi/lo split (3 MFMAs ~ fp32 precision).
// MODE 0: head-split bf16 hi/lo planes out[bh][s(SEQ)][64]
// MODE 1: plain fp32 out[m][1024]
// MODE 2: transposed bf16 hi/lo planes out[bh][dh][1024(pad)]
// ---------------------------------------------------------------
template<int MODE>
__global__ __launch_bounds__(256)
void gemm_mfma_kernel(const float* __restrict__ X, const float* __restrict__ W,
                      const float* __restrict__ bias, float* __restrict__ out32,
                      __bf16* __restrict__ outHi, __bf16* __restrict__ outLo,
                      int M, int rows)
{
    __shared__ __align__(16) __bf16 As[4096];
    __shared__ __align__(16) __bf16 Bs[4096];

    const int t  = threadIdx.x;
    const int w  = t >> 6, l = t & 63;
    const int lr = l & 15, ls = l >> 4;
    const int m0 = blockIdx.y * 64, n0 = blockIdx.x * 64;
    const int sr  = t >> 2;
    const int skq = t & 3;

    f32x4 acc[4];
#pragma unroll
    for (int ct = 0; ct < 4; ++ct) acc[ct] = f32x4{0.f, 0.f, 0.f, 0.f};

    const int ar   = w * 16 + lr;
    const int a_hi = ar * 128 + (((2 * ls    ) ^ (ar & 7)) << 4);
    const int a_lo = ar * 128 + (((2 * ls + 1) ^ (ar & 7)) << 4);
    const int st_hi = sr * 128 + (((2 * skq    ) ^ (sr & 7)) << 4);
    const int st_lo = sr * 128 + (((2 * skq + 1) ^ (sr & 7)) << 4);

    for (int k0 = 0; k0 < DMODEL; k0 += 32) {
        __syncthreads();
        {
            float xv[8];
            if (m0 + sr < M) {
                float4 v0 = *(const float4*)&X[(size_t)(m0 + sr) * DMODEL + k0 + skq * 8];
                float4 v1 = *(const float4*)&X[(size_t)(m0 + sr) * DMODEL + k0 + skq * 8 + 4];
                xv[0] = v0.x; xv[1] = v0.y; xv[2] = v0.z; xv[3] = v0.w;
                xv[4] = v1.x; xv[5] = v1.y; xv[6] = v1.z; xv[7] = v1.w;
            } else {
#pragma unroll
                for (int e = 0; e < 8; ++e) xv[e] = 0.f;
            }
            bf16x8 h8, l8;
#pragma unroll
            for (int e = 0; e < 8; ++e) {
                __bf16 hb = (__bf16)xv[e];
                h8[e] = hb;
                l8[e] = (__bf16)(xv[e] - (float)hb);
            }
            *(bf16x8*)((char*)As + st_hi) = h8;
            *(bf16x8*)((char*)As + st_lo) = l8;
        }
        {
            float wv[8];
#pragma unroll
            for (int e = 0; e < 8; ++e)
                wv[e] = W[(size_t)(k0 + skq * 8 + e) * DMODEL + n0 + sr];
            bf16x8 h8, l8;
#pragma unroll
            for (int e = 0; e < 8; ++e) {
                __bf16 hb = (__bf16)wv[e];
                h8[e] = hb;
                l8[e] = (__bf16)(wv[e] - (float)hb);
            }
            *(bf16x8*)((char*)Bs + st_hi) = h8;
            *(bf16x8*)((char*)Bs + st_lo) = l8;
        }
        __syncthreads();

        const bf16x8 ah = *(const bf16x8*)((const char*)As + a_hi);
        const bf16x8 al = *(const bf16x8*)((const char*)As + a_lo);
#pragma unroll
        for (int ct = 0; ct < 4; ++ct) {
            const int bc   = ct * 16 + lr;
            const int b_hi = bc * 128 + (((2 * ls    ) ^ (bc & 7)) << 4);
            const int b_lo = bc * 128 + (((2 * ls + 1) ^ (bc & 7)) << 4);
            const bf16x8 bh = *(const bf16x8*)((const char*)Bs + b_hi);
            const bf16x8 bl = *(const bf16x8*)((const char*)Bs + b_lo);
            acc[ct] = __builtin_amdgcn_mfma_f32_16x16x32_bf16(ah, bh, acc[ct], 0, 0, 0);
            acc[ct] = __builtin_amdgcn_mfma_f32_16x16x32_bf16(al, bh, acc[ct], 0, 0, 0);
            acc[ct] = __builtin_amdgcn_mfma_f32_16x16x32_bf16(ah, bl, acc[ct], 0, 0, 0);
        }
    }

#pragma unroll
    for (int ct = 0; ct < 4; ++ct) {
        const int n = n0 + ct * 16 + lr;
        const float bv = bias[n];
#pragma unroll
        for (int j = 0; j < 4; ++j) {
            const int m = m0 + w * 16 + ls * 4 + j;
            if (m >= M) continue;
            const float val = acc[ct][j] + bv;
            if (MODE == 1) {
                out32[(size_t)m * DMODEL + n] = val;
            } else {
                const int bb = m / rows, s = m - bb * rows;
                const __bf16 hb = (__bf16)val;
                const __bf16 lb = (__bf16)(val - (float)hb);
                size_t idx;
                if (MODE == 0)
                    idx = (((size_t)(bb * HN + (n >> 6)) * SEQ + s) << 6) + (n & 63);
                else
                    idx = (((size_t)(bb * HN + (n >> 6)) * DH + (n & 63)) << 10) + s;
                outHi[idx] = hb; outLo[idx] = lb;
            }
        }
    }
}

// ---------------------------------------------------------------
// Pack mask -> bitmask [row][32 u32]. Wave per row.
// ---------------------------------------------------------------
__global__ __launch_bounds__(256)
void mask_pack_kernel(const int* __restrict__ mask, unsigned int* __restrict__ mb)
{
    const int row = blockIdx.x * 4 + (threadIdx.x >> 6);
    const int l   = threadIdx.x & 63;
    if (row >= 2 * SM1) return;
    const int* mrow = mask + (size_t)row * SM1;
    unsigned int* out = mb + (size_t)row * 32;
#pragma unroll
    for (int i = 0; i < 16; ++i) {
        const int c = i * 64 + l;
        const bool mv = (c < SM1) && (mrow[c] != 0);
        unsigned long long bal = __ballot(mv);
        if (l == 0) {
            out[i * 2]     = (unsigned int)bal;
            out[i * 2 + 1] = (unsigned int)(bal >> 32);
        }
    }
}

// ---------------------------------------------------------------
// Fully fused attention (flash-style recompute, 2 passes).
// Block = 64 att-rows x all 1023 keys x one (b,h). 512 thr / 8 waves:
// wave w: row group g=w&3 (16 rows), col-half / PV-parity p=w>>2.
// Pass 1: QK (LDS-staged K, hi/lo MFMA) -> relu/mask -> exp -> row sums.
// Pass 2: recompute QK, scale by inv, write weights once (coalesced,
// nontemporal), PV from LDS exp tile (bf16 hi/lo) x LDS-staged V.
// ---------------------------------------------------------------
__global__ __launch_bounds__(512)
void attn_fused_kernel(const __bf16* __restrict__ qhi, const __bf16* __restrict__ qlo,
                       const __bf16* __restrict__ khi, const __bf16* __restrict__ klo,
                       const __bf16* __restrict__ vthi, const __bf16* __restrict__ vtlo,
                       const unsigned int* __restrict__ mbG,
                       float* __restrict__ att, float* __restrict__ ctx)
{
    __shared__ __align__(16) char Qs[64 * ROWB];    // Q hi/lo; reused as red [64][68] f32
    __shared__ __align__(16) char KV[35840];        // K tile (128*272) / V tile (64*560)
    __shared__ __align__(16) float E[64 * 132];     // exp tile f32
    __shared__ float invs[64];
    __shared__ float partial[64][2];
    __shared__ unsigned int mbits[64][4];

    const int b = blockIdx.z, h = blockIdx.y, bh = b * HN + h;
    const int q0 = blockIdx.x * 64;
    const int t = threadIdx.x, w = t >> 6, l = t & 63;
    const int lr = l & 15, ls = l >> 4;
    const int g = w & 3, p = w >> 2;

    // ---- stage Q (64 rows x 16 chunks of 16B) ----
#pragma unroll
    for (int it = 0; it < 2; ++it) {
        const int id = t + it * 512;
        const int r = id >> 4, cw = id & 15;
        const int plane = cw >> 3, s = cw & 7;
        int qrow = q0 + r + 1; if (qrow > 1023) qrow = 1023;
        const __bf16* src = plane ? qlo : qhi;
        bf16x8 vv = *(const bf16x8*)&src[((size_t)bh * SEQ + qrow) * DH + s * 8];
        *(bf16x8*)(Qs + r * ROWB + cw * 16) = vv;
    }
    __syncthreads();

    // ---- A fragments (held both passes) ----
    const int ar = g * 16 + lr;
    const bf16x8 a0h = *(const bf16x8*)(Qs + ar * ROWB + ls * 16);
    const bf16x8 a1h = *(const bf16x8*)(Qs + ar * ROWB + (4 + ls) * 16);
    const bf16x8 a0l = *(const bf16x8*)(Qs + ar * ROWB + (8 + ls) * 16);
    const bf16x8 a1l = *(const bf16x8*)(Qs + ar * ROWB + (12 + ls) * 16);

    // ================= pass 1: row sums of exp =================
    float rsum[4] = {0.f, 0.f, 0.f, 0.f};
    for (int kt = 0; kt < 8; ++kt) {
        const int c0 = kt * 128;
        __syncthreads();
        if (t < 256) {
            const int r = t >> 2, wd = t & 3;
            const int rr = q0 + r;
            mbits[r][wd] = (rr < SM1) ? mbG[((size_t)b * SM1 + rr) * 32 + kt * 4 + wd] : 0u;
        }
#pragma unroll
        for (int it = 0; it < 4; ++it) {
            const int id = t + it * 512;
            const int r = id >> 4, cw = id & 15;
            const int plane = cw >> 3, s = cw & 7;
            int krow = c0 + r; if (krow > 1023) krow = 1023;
            const __bf16* src = plane ? klo : khi;
            bf16x8 vv = *(const bf16x8*)&src[((size_t)bh * SEQ + krow) * DH + s * 8];
            *(bf16x8*)(KV + r * ROWB + cw * 16) = vv;
        }
        __syncthreads();

#pragma unroll
        for (int i = 0; i < 4; ++i) {
            const int ct = p * 4 + i;
            const int kr = ct * 16 + lr;
            const bf16x8 b0h = *(const bf16x8*)(KV + kr * ROWB + ls * 16);
            const bf16x8 b1h = *(const bf16x8*)(KV + kr * ROWB + (4 + ls) * 16);
            const bf16x8 b0l = *(const bf16x8*)(KV + kr * ROWB + (8 + ls) * 16);
            const bf16x8 b1l = *(const bf16x8*)(KV + kr * ROWB + (12 + ls) * 16);

            f32x4 acc = {0.f, 0.f, 0.f, 0.f};
            acc = __builtin_amdgcn_mfma_f32_16x16x32_bf16(a0h, b0h, acc, 0, 0, 0);
            acc = __builtin_amdgcn_mfma_f32_16x16x32_bf16(a0l, b0h, acc, 0, 0, 0);
            acc = __builtin_amdgcn_mfma_f32_16x16x32_bf16(a0h, b0l, acc, 0, 0, 0);
            acc = __builtin_amdgcn_mfma_f32_16x16x32_bf16(a1h, b1h, acc, 0, 0, 0);
            acc = __builtin_amdgcn_mfma_f32_16x16x32_bf16(a1l, b1h, acc, 0, 0, 0);
            acc = __builtin_amdgcn_mfma_f32_16x16x32_bf16(a1h, b1l, acc, 0, 0, 0);

            const int c = c0 + ct * 16 + lr;
#pragma unroll
            for (int j = 0; j < 4; ++j) {
                const int r = q0 + g * 16 + ls * 4 + j;
                if (r < SM1 && c < SM1) {
                    float sc = fmaxf(acc[j] * 0.125f, 0.f);
                    const unsigned int wm = mbits[g * 16 + ls * 4 + j][ct >> 1];
                    if ((wm >> ((ct & 1) * 16 + lr)) & 1u) sc = -1e9f;
                    rsum[j] += __expf(sc);
                }
            }
        }
    }
#pragma unroll
    for (int j = 0; j < 4; ++j) {
        rsum[j] += __shfl_xor(rsum[j], 1, 64);
        rsum[j] += __shfl_xor(rsum[j], 2, 64);
        rsum[j] += __shfl_xor(rsum[j], 4, 64);
        rsum[j] += __shfl_xor(rsum[j], 8, 64);
    }
    if (lr == 0) {
#pragma unroll
        for (int j = 0; j < 4; ++j)
            partial[g * 16 + ls * 4 + j][p] = rsum[j];
    }
    __syncthreads();
    if (t < 64) {
        const float s = partial[t][0] + partial[t][1];
        invs[t] = (q0 + t < SM1) ? 1.0f / s : 0.f;
    }
    __syncthreads();
    float inv4[4];
#pragma unroll
    for (int j = 0; j < 4; ++j) inv4[j] = invs[g * 16 + ls * 4 + j];

    // ================= pass 2: weights + PV =================
    f32x4 oacc[4];
#pragma unroll
    for (int ct = 0; ct < 4; ++ct) oacc[ct] = f32x4{0.f, 0.f, 0.f, 0.f};

    for (int kt = 0; kt < 8; ++kt) {
        const int c0 = kt * 128;
        __syncthreads();   // A: KV free (prev PV done)
        if (t < 256) {
            const int r = t >> 2, wd = t & 3;
            const int rr = q0 + r;
            mbits[r][wd] = (rr < SM1) ? mbG[((size_t)b * SM1 + rr) * 32 + kt * 4 + wd] : 0u;
        }
#pragma unroll
        for (int it = 0; it < 4; ++it) {
            const int id = t + it * 512;
            const int r = id >> 4, cw = id & 15;
            const int plane = cw >> 3, s = cw & 7;
            int krow = c0 + r; if (krow > 1023) krow = 1023;
            const __bf16* src = plane ? klo : khi;
            bf16x8 vv = *(const bf16x8*)&src[((size_t)bh * SEQ + krow) * DH + s * 8];
            *(bf16x8*)(KV + r * ROWB + cw * 16) = vv;
        }
        __syncthreads();   // B

#pragma unroll
        for (int i = 0; i < 4; ++i) {
            const int ct = p * 4 + i;
            const int kr = ct * 16 + lr;
            const bf16x8 b0h = *(const bf16x8*)(KV + kr * ROWB + ls * 16);
            const bf16x8 b1h = *(const bf16x8*)(KV + kr * ROWB + (4 + ls) * 16);
            const bf16x8 b0l = *(const bf16x8*)(KV + kr * ROWB + (8 + ls) * 16);
            const bf16x8 b1l = *(const bf16x8*)(KV + kr * ROWB + (12 + ls) * 16);

            f32x4 acc = {0.f, 0.f, 0.f, 0.f};
            acc = __builtin_amdgcn_mfma_f32_16x16x32_bf16(a0h, b0h, acc, 0, 0, 0);
            acc = __builtin_amdgcn_mfma_f32_16x16x32_bf16(a0l, b0h, acc, 0, 0, 0);
            acc = __builtin_amdgcn_mfma_f32_16x16x32_bf16(a0h, b0l, acc, 0, 0, 0);
            acc = __builtin_amdgcn_mfma_f32_16x16x32_bf16(a1h, b1h, acc, 0, 0, 0);
            acc = __builtin_amdgcn_mfma_f32_16x16x32_bf16(a1l, b1h, acc, 0, 0, 0);
            acc = __builtin_amdgcn_mfma_f32_16x16x32_bf16(a1h, b1l, acc, 0, 0, 0);

            const int c = c0 + ct * 16 + lr;
#pragma unroll
            for (int j = 0; j < 4; ++j) {
                const int r = q0 + g * 16 + ls * 4 + j;
                float v = 0.f;
                if (r < SM1 && c < SM1) {
                    float sc = fmaxf(acc[j] * 0.125f, 0.f);
                    const unsigned int wm = mbits[g * 16 + ls * 4 + j][ct >> 1];
                    if ((wm >> ((ct & 1) * 16 + lr)) & 1u) sc = -1e9f;
                    v = __expf(sc) * inv4[j];
                }
                E[(g * 16 + ls * 4 + j) * 132 + ct * 16 + lr] = v;
            }
        }
        __syncthreads();   // C: E complete, K consumed

        // ---- stage V (overwrites K area) ----
#pragma unroll
        for (int it = 0; it < 4; ++it) {
            const int id = t + it * 512;
            const int dr = id >> 5, cw = id & 31;
            const int plane = cw >> 4, s8 = cw & 15;
            const __bf16* src = plane ? vtlo : vthi;
            bf16x8 vv = *(const bf16x8*)&src[(((size_t)bh * DH + dr) << 10) + c0 + s8 * 8];
            *(bf16x8*)(KV + dr * VROWB + cw * 16) = vv;
        }
        // ---- coalesced weight write-out from E ----
#pragma unroll
        for (int it = 0; it < 4; ++it) {
            const int id = t + it * 512;
            const int r = id >> 5, q4 = id & 31;
            const int rr = q0 + r, cc = c0 + q4 * 4;
            if (rr < SM1) {
                f32x4 vv = *(const f32x4*)&E[r * 132 + q4 * 4];
                float* dst = &att[((size_t)bh * SM1 + rr) * SM1 + cc];
                if (cc + 4 <= SM1) {
                    __builtin_nontemporal_store(vv, (f32x4*)dst);
                } else {
                    if (cc + 0 < SM1) dst[0] = vv.x;
                    if (cc + 1 < SM1) dst[1] = vv.y;
                    if (cc + 2 < SM1) dst[2] = vv.z;
                }
            }
        }
        __syncthreads();   // D: V staged, E stable

        // ---- PV: parity p handles keys p*64..p*64+63 of the tile ----
#pragma unroll
        for (int m = 0; m < 2; ++m) {
            const int ks = p * 2 + m;
            const int pr = g * 16 + lr;
            const f32x4 p0 = *(const f32x4*)&E[pr * 132 + ks * 32 + ls * 8];
            const f32x4 p1 = *(const f32x4*)&E[pr * 132 + ks * 32 + ls * 8 + 4];
            float pf[8] = {p0.x, p0.y, p0.z, p0.w, p1.x, p1.y, p1.z, p1.w};
            bf16x8 ph, pl;
#pragma unroll
            for (int e = 0; e < 8; ++e) {
                const __bf16 hb = (__bf16)pf[e];
                ph[e] = hb;
                pl[e] = (__bf16)(pf[e] - (float)hb);
            }
#pragma unroll
            for (int ct = 0; ct < 4; ++ct) {
                const int vr = ct * 16 + lr;
                const bf16x8 vh = *(const bf16x8*)(KV + vr * VROWB + (ks * 4 + ls) * 16);
                const bf16x8 vl = *(const bf16x8*)(KV + vr * VROWB + (16 + ks * 4 + ls) * 16);
                oacc[ct] = __builtin_amdgcn_mfma_f32_16x16x32_bf16(ph, vh, oacc[ct], 0, 0, 0);
                oacc[ct] = __builtin_amdgcn_mfma_f32_16x16x32_bf16(pl, vh, oacc[ct], 0, 0, 0);
                oacc[ct] = __builtin_amdgcn_mfma_f32_16x16x32_bf16(ph, vl, oacc[ct], 0, 0, 0);
            }
        }
    }

    // ---- cross-parity reduce (reuse Qs) and ctx write ----
    __syncthreads();
    float* red = (float*)Qs;   // [64][68]
    if (p == 1) {
#pragma unroll
        for (int ct = 0; ct < 4; ++ct)
#pragma unroll
            for (int j = 0; j < 4; ++j)
                red[(g * 16 + ls * 4 + j) * 68 + ct * 16 + lr] = oacc[ct][j];
    }
    __syncthreads();
    if (p == 0) {
#pragma unroll
        for (int ct = 0; ct < 4; ++ct)
#pragma unroll
            for (int j = 0; j < 4; ++j) {
                const int r = q0 + g * 16 + ls * 4 + j;
                if (r < SM1)
                    ctx[((size_t)b * SM1 + r) * DMODEL + h * DH + ct * 16 + lr] =
                        oacc[ct][j] + red[(g * 16 + ls * 4 + j) * 68 + ct * 16 + lr];
            }
    }
}

// ---------------------------------------------------------------
extern "C" void kernel_launch(void* const* d_in, const int* in_sizes, int n_in,
                              void* d_out, int out_size, void* d_ws, size_t ws_size,
                              hipStream_t stream) {
    const float* q    = (const float*)d_in[0];
    const float* k    = (const float*)d_in[1];
    const float* v    = (const float*)d_in[2];
    const int*   mask = (const int*)  d_in[4];
    const float* Wq   = (const float*)d_in[5];
    const float* bq   = (const float*)d_in[6];
    const float* Wk   = (const float*)d_in[7];
    const float* bk   = (const float*)d_in[8];
    const float* Wv   = (const float*)d_in[9];
    const float* bv   = (const float*)d_in[10];
    const float* Wo   = (const float*)d_in[11];
    const float* bo   = (const float*)d_in[12];

    float* out0 = (float*)d_out;                       // [2,1023,1024]
    float* att  = out0 + (size_t)2 * SM1 * DMODEL;     // [2,16,1023,1023]

    const size_t NQ  = (size_t)2 * HN * SEQ * DH;      // 2,097,152 per plane
    const size_t NVT = (size_t)2 * HN * DH * 1024;     // 2,097,152 per plane
    __bf16* ws16 = (__bf16*)d_ws;
    __bf16* qhi  = ws16;
    __bf16* qlo  = qhi + NQ;
    __bf16* khi  = qlo + NQ;
    __bf16* klo  = khi + NQ;
    __bf16* vthi = klo + NQ;
    __bf16* vtlo = vthi + NVT;
    float*  ctx  = (float*)(vtlo + NVT);               // [2,1023,1024]
    unsigned int* mbG = (unsigned int*)(ctx + (size_t)2 * SM1 * DMODEL); // [2046][32]

    (void)hipMemsetAsync(vthi, 0, 2 * NVT * sizeof(__bf16), stream);

    mask_pack_kernel<<<dim3(512), 256, 0, stream>>>(mask, mbG);

    gemm_mfma_kernel<0><<<dim3(16, 32), 256, 0, stream>>>(q, Wq, bq, nullptr, qhi, qlo, 2 * SEQ, SEQ);
    gemm_mfma_kernel<0><<<dim3(16, 32), 256, 0, stream>>>(k, Wk, bk, nullptr, khi, klo, 2 * SEQ, SEQ);
    gemm_mfma_kernel<2><<<dim3(16, 32), 256, 0, stream>>>(v, Wv, bv, nullptr, vthi, vtlo, 2 * SM1, SM1);

    attn_fused_kernel<<<dim3(16, HN, 2), 512, 0, stream>>>(qhi, qlo, khi, klo, vthi, vtlo, mbG, att, ctx);

    gemm_mfma_kernel<1><<<dim3(16, 32), 256, 0, stream>>>(ctx, Wo, bo, out0, nullptr, nullptr, 2 * SM1, SM1);
}